// Round 3
// baseline (909.432 us; speedup 1.0000x reference)
//
#include <hip/hip_runtime.h>

#define HDIM 256
#define MTILE 64
#define NITER 4          // row-tiles per scores block (256 rows/block)
#define APITCH 264       // 256 + 8 pad (shorts)
#define PROWS 512
#define CHUNK 32         // rows per fast-path chunk in k_pool (16 per parity)

typedef __attribute__((ext_vector_type(8))) short short8;
typedef __attribute__((ext_vector_type(4))) short short4v;
typedef __attribute__((ext_vector_type(4))) float floatx4;

__device__ __forceinline__ unsigned short f2bf(float f){
  unsigned u = __float_as_uint(f);
  u += 0x7FFFu + ((u>>16)&1u);
  return (unsigned short)(u>>16);
}
__device__ __forceinline__ float bf2f(unsigned short h){
  return __uint_as_float(((unsigned)h)<<16);
}
__device__ __forceinline__ unsigned fkey(float f){
  unsigned u = __float_as_uint(f);
  return u ^ ((unsigned)((int)u>>31) | 0x80000000u);
}
__device__ __forceinline__ float fdec(unsigned u){
  unsigned b = (u & 0x80000000u) ? (u & 0x7FFFFFFFu) : ~u;
  return __uint_as_float(b);
}

__global__ void k_zero(float* __restrict__ p, int n){
  int i = blockIdx.x*256 + threadIdx.x;
  if (i < n) p[i] = 0.f;
}

__global__ void k_prep(const float* __restrict__ w1, unsigned short* __restrict__ w1t){
  int col = blockIdx.x, k = threadIdx.x;
  w1t[col*HDIM + k] = f2bf(w1[k*HDIM + col]);
}

__global__ void k_bounds(const int* __restrict__ batch, int* __restrict__ segstart,
                         int n, int B){
  int i = blockIdx.x*256 + threadIdx.x;
  if (i >= n) return;
  int b = batch[i];
  int prev = (i == 0) ? -1 : batch[i-1];
  if (prev != b) for (int q = prev+1; q <= b; ++q) segstart[q] = i;
  if (i == n-1) for (int q = b+1; q <= B; ++q) segstart[q] = n;
}

// s = tanh(x@W1+b1)@W2+b2 via bf16 MFMA; also emits bf16 copy of x
__launch_bounds__(256)
__global__ void k_scores(const float* __restrict__ x,
                         const unsigned short* __restrict__ w1t,
                         const float* __restrict__ b1,
                         const float* __restrict__ w2,
                         const float* __restrict__ b2,
                         float* __restrict__ s,
                         unsigned short* __restrict__ xbf, int n)
{
  __shared__ unsigned short As[MTILE*APITCH];
  __shared__ float sp[4][MTILE];
  const int t = threadIdx.x;
  const int wv = t>>6;
  const int lane = t&63;
  const int l15 = lane&15;
  const int quad = lane>>4;
  const long long base = (long long)blockIdx.x * (MTILE*NITER);

  // B fragments: wave wv owns cols [wv*64, wv*64+64), all K in registers
  short8 bf[8][4];
  float b1v[4], w2v[4];
  const int cb = wv*64;
  #pragma unroll
  for (int ct=0; ct<4; ++ct){
    int col = cb + ct*16 + l15;
    b1v[ct] = b1[col];
    w2v[ct] = w2[col];
    #pragma unroll
    for (int kc=0; kc<8; ++kc)
      bf[kc][ct] = *(const short8*)(w1t + (size_t)col*HDIM + kc*32 + quad*8);
  }

  const float4* x4 = (const float4*)x;
  for (int it = 0; it < NITER; ++it){
    const long long node0 = base + (long long)it*MTILE;
    if (node0 >= n) break;

    #pragma unroll
    for (int j=0; j<MTILE/4; ++j){
      int f = j*256 + t;
      int row = f>>6, c4 = f&63;
      long long gr = node0 + row;
      float4 v = make_float4(0.f,0.f,0.f,0.f);
      if (gr < n) v = x4[gr*(HDIM/4) + c4];
      short4v p;
      p.x=(short)f2bf(v.x); p.y=(short)f2bf(v.y); p.z=(short)f2bf(v.z); p.w=(short)f2bf(v.w);
      *(short4v*)(As + row*APITCH + c4*4) = p;
      if (gr < n) *(short4v*)(xbf + gr*HDIM + c4*4) = p;   // bf16 copy for k_pool
    }
    __syncthreads();

    #pragma unroll 1
    for (int rt=0; rt<MTILE/16; ++rt){
      floatx4 acc[4];
      #pragma unroll
      for (int ct=0;ct<4;++ct) acc[ct] = (floatx4){0.f,0.f,0.f,0.f};
      #pragma unroll
      for (int kc=0; kc<8; ++kc){
        short8 a = *(const short8*)(As + (rt*16 + l15)*APITCH + kc*32 + quad*8);
        #pragma unroll
        for (int ct=0; ct<4; ++ct)
          acc[ct] = __builtin_amdgcn_mfma_f32_16x16x32_bf16(a, bf[kc][ct], acc[ct], 0, 0, 0);
      }
      float part[4] = {0.f,0.f,0.f,0.f};
      #pragma unroll
      for (int ct=0; ct<4; ++ct){
        #pragma unroll
        for (int r=0; r<4; ++r){
          float h = acc[ct][r] + b1v[ct];
          float z = fminf(fmaxf(2.f*h, -30.f), 30.f);
          float e = __expf(z);
          part[r] += __fdividef(e-1.f, e+1.f) * w2v[ct];
        }
      }
      #pragma unroll
      for (int off=8; off>=1; off>>=1){
        #pragma unroll
        for (int r=0;r<4;++r) part[r] += __shfl_xor(part[r], off, 64);
      }
      if (l15==0){
        #pragma unroll
        for (int r=0;r<4;++r) sp[wv][rt*16 + quad*4 + r] = part[r];
      }
    }
    __syncthreads();
    if (t < MTILE){
      long long gr = node0 + t;
      if (gr < n) s[gr] = sp[0][t]+sp[1][t]+sp[2][t]+sp[3][t] + b2[0];
    }
  }
}

// per-segment softmax: max, e=exp(s-m) in place, denom, counts
__global__ void k_seg(float* __restrict__ s, const int* __restrict__ segstart,
                      float* __restrict__ denom, float* __restrict__ counts){
  __shared__ float red[4];
  const int b = blockIdx.x;
  const int t = threadIdx.x;
  const int lane = t&63, wv = t>>6;
  const int start = segstart[b], end = segstart[b+1];

  float m = -INFINITY;
  for (int i = start + t; i < end; i += 256) m = fmaxf(m, s[i]);
  #pragma unroll
  for (int off=32; off>=1; off>>=1) m = fmaxf(m, __shfl_xor(m, off, 64));
  if (lane==0) red[wv] = m;
  __syncthreads();
  m = fmaxf(fmaxf(red[0],red[1]), fmaxf(red[2],red[3]));

  float acc = 0.f;
  for (int i = start + t; i < end; i += 256){
    float e = __expf(s[i] - m);
    s[i] = e; acc += e;
  }
  #pragma unroll
  for (int off=32; off>=1; off>>=1) acc += __shfl_xor(acc, off, 64);
  __syncthreads();
  if (lane==0) red[wv] = acc;
  __syncthreads();
  if (t==0){
    float total = red[0]+red[1]+red[2]+red[3];
    denom[b] = (total > 0.f) ? total : 1.f;
    counts[b] = (float)(end - start);
  }
}

// pooling from bf16 x: thread t owns 2 cols, wave-uniform row parity
__launch_bounds__(256)
__global__ void k_pool(const unsigned short* __restrict__ xbf, const int* __restrict__ batch,
                       const float* __restrict__ e, const float* __restrict__ denom,
                       float* __restrict__ sums, unsigned* __restrict__ maxu,
                       float* __restrict__ attn, int n){
  const int t = threadIdx.x;
  const int col = (t&127)*2;
  const int ro = t>>7;                 // row parity (uniform per wave)
  long long r0 = (long long)blockIdx.x * PROWS;
  if (r0 >= n) return;
  long long r1 = r0 + PROWS; if (r1 > n) r1 = n;

  int curb = batch[r0];
  float rd = 1.f/denom[curb];
  float s0=0.f,s1=0.f,a0=0.f,a1=0.f,m0=-INFINITY,m1=-INFINITY;

  long long i = r0;
  while (i < r1){
    if (i + CHUNK <= r1 && batch[i + CHUNK - 1] == curb){
      #pragma unroll
      for (int k=0;k<CHUNK/2;++k){
        long long row = i + 2*k + ro;
        unsigned u = *(const unsigned*)(xbf + row*HDIM + col);
        float w = e[row]*rd;
        float v0 = bf2f((unsigned short)(u & 0xFFFFu));
        float v1 = bf2f((unsigned short)(u >> 16));
        s0 += v0; s1 += v1; a0 += v0*w; a1 += v1*w;
        m0 = fmaxf(m0, v0); m1 = fmaxf(m1, v1);
      }
      i += CHUNK;
    } else {
      // slow path: this thread's parity rows, one pair at a time
      long long row = i + ro;
      if (row < r1){
        int b = batch[row];
        if (b != curb){
          atomicAdd(&sums[(size_t)curb*HDIM + col],   s0);
          atomicAdd(&sums[(size_t)curb*HDIM + col+1], s1);
          atomicAdd(&attn[(size_t)curb*HDIM + col],   a0);
          atomicAdd(&attn[(size_t)curb*HDIM + col+1], a1);
          if (m0 > -INFINITY) atomicMax(&maxu[(size_t)curb*HDIM + col],   fkey(m0));
          if (m1 > -INFINITY) atomicMax(&maxu[(size_t)curb*HDIM + col+1], fkey(m1));
          curb=b; rd=1.f/denom[b]; s0=s1=a0=a1=0.f; m0=m1=-INFINITY;
        }
        unsigned u = *(const unsigned*)(xbf + row*HDIM + col);
        float w = e[row]*rd;
        float v0 = bf2f((unsigned short)(u & 0xFFFFu));
        float v1 = bf2f((unsigned short)(u >> 16));
        s0 += v0; s1 += v1; a0 += v0*w; a1 += v1*w;
        m0 = fmaxf(m0, v0); m1 = fmaxf(m1, v1);
      }
      i += 2;
    }
  }
  atomicAdd(&sums[(size_t)curb*HDIM + col],   s0);
  atomicAdd(&sums[(size_t)curb*HDIM + col+1], s1);
  atomicAdd(&attn[(size_t)curb*HDIM + col],   a0);
  atomicAdd(&attn[(size_t)curb*HDIM + col+1], a1);
  if (m0 > -INFINITY) atomicMax(&maxu[(size_t)curb*HDIM + col],   fkey(m0));
  if (m1 > -INFINITY) atomicMax(&maxu[(size_t)curb*HDIM + col+1], fkey(m1));
}

__global__ void k_fin(const float* __restrict__ sums, const unsigned* __restrict__ maxu,
                      const float* __restrict__ attn, const float* __restrict__ counts,
                      float* __restrict__ out, int bcount){
  int idx = blockIdx.x*256 + threadIdx.x;
  int total = bcount*3*HDIM;
  if (idx >= total) return;
  int b = idx / (3*HDIM);
  int c = idx - b*(3*HDIM);
  float cnt = counts[b];
  float v;
  if (c < HDIM)        v = sums[(size_t)b*HDIM + c] / fmaxf(cnt, 1.f);
  else if (c < 2*HDIM) v = (cnt > 0.f) ? fdec(maxu[(size_t)b*HDIM + (c-HDIM)]) : 0.f;
  else                 v = attn[(size_t)b*HDIM + (c-2*HDIM)];
  out[idx] = v;
}

extern "C" void kernel_launch(void* const* d_in, const int* in_sizes, int n_in,
                              void* d_out, int out_size, void* d_ws, size_t ws_size,
                              hipStream_t stream){
  const float* x   = (const float*)d_in[0];
  const int* batch = (const int*)d_in[1];
  const float* W1  = (const float*)d_in[2];
  const float* b1  = (const float*)d_in[3];
  const float* W2  = (const float*)d_in[4];
  const float* b2  = (const float*)d_in[5];
  float* out = (float*)d_out;
  const int n = in_sizes[1];
  const int B = out_size / (3*HDIM);

  char* w = (char*)d_ws;
  unsigned short* xbf = (unsigned short*)w;                 // n*HDIM bf16 (256 MB)
  size_t off = ((size_t)n*HDIM*2 + 255) & ~(size_t)255;
  unsigned short* W1T = (unsigned short*)(w + off);
  off += (size_t)HDIM*HDIM*2;
  float* s = (float*)(w + off);
  off += (size_t)((n+3)&~3)*4;
  int* segstart = (int*)(w + off);
  off += (size_t)((B+4)&~3)*4;
  float* stats = (float*)(w + off);
  float* denom  = stats;
  float* counts = stats + B;
  float* sums   = stats + 2*B;
  unsigned* maxu = (unsigned*)(stats + 2*B + (size_t)B*HDIM);
  float* attn   = stats + 2*B + 2*(size_t)B*HDIM;
  int zerowords = 3*B*HDIM;

  hipLaunchKernelGGL(k_zero, dim3((zerowords+255)/256), dim3(256), 0, stream, sums, zerowords);
  hipLaunchKernelGGL(k_prep, dim3(HDIM), dim3(HDIM), 0, stream, W1, W1T);
  hipLaunchKernelGGL(k_bounds, dim3((n+255)/256), dim3(256), 0, stream, batch, segstart, n, B);
  hipLaunchKernelGGL(k_scores, dim3((n + MTILE*NITER - 1)/(MTILE*NITER)), dim3(256), 0, stream,
                     x, W1T, b1, W2, b2, s, xbf, n);
  hipLaunchKernelGGL(k_seg, dim3(B), dim3(256), 0, stream, s, segstart, denom, counts);
  hipLaunchKernelGGL(k_pool, dim3((int)((n+PROWS-1)/PROWS)), dim3(256), 0, stream,
                     xbf, batch, s, denom, sums, maxu, attn, n);
  hipLaunchKernelGGL(k_fin, dim3((out_size+255)/256), dim3(256), 0, stream,
                     sums, maxu, attn, counts, out, B);
}